// Round 5
// baseline (259.977 us; speedup 1.0000x reference)
//
#include <hip/hip_runtime.h>
#include <cstddef>

// Problem shapes (fixed by reference)
#define NBH  1024   // B*H
#define Mm   196
#define Dd   128
#define MIDe 64
#define DVv  128
#define NMT  13     // ceil(196/16) m-tiles
#define SLD  208    // padded spatial-logit row length

typedef __attribute__((ext_vector_type(8))) short bf16x8;  // 8 bf16 in 4 VGPRs
typedef __attribute__((ext_vector_type(4))) float f32x4;   // MFMA C/D frag

// Workspace layout (requires ~20.1 MB):
//  wqF : bf16 B-fragments, [bh][ks*4+nt][lane] x 8 shorts  = 16 MB
//  sW  : spatial logits    [bh][SLD]                        = 852 KB
//  poolW: pool partials    [bh][mt][64]                     = 3.4 MB
#define WQ_SHORTS   ((size_t)NBH * 16 * 64 * 8)
#define SW_FLOATS   ((size_t)NBH * SLD)
#define POOL_FLOATS ((size_t)NBH * NMT * 64)

__device__ __forceinline__ short f2bf(float x) {           // fp32 -> bf16 RNE
    union { float f; unsigned u; } v; v.f = x;
    return (short)((v.u + 0x7FFFu + ((v.u >> 16) & 1u)) >> 16);
}

__device__ __forceinline__ float waveReduceSum(float v) {
#pragma unroll
    for (int off = 32; off > 0; off >>= 1) v += __shfl_xor(v, off, 64);
    return v;
}

__device__ __forceinline__ float waveReduceMax(float v) {
#pragma unroll
    for (int off = 32; off > 0; off >>= 1) v = fmaxf(v, __shfl_xor(v, off, 64));
    return v;
}

// ---------------- K0: build Wq fragments into workspace ----------------
// wqT[e][d] = bf16(q[d] * W_basic[d][e]); then each wave (= ks) emits its
// 4 nt-fragments in MFMA B-operand lane order so K1 loads are 1 KB/instr
// perfectly coalesced.
__global__ __launch_bounds__(256)
void build_wq(const float* __restrict__ query,
              const float* __restrict__ W_basic,
              short* __restrict__ wqF)
{
    __shared__ float qS[Dd];
    __shared__ short wqT[MIDe][136];    // +8-short pad: frag reads 8-round optimal

    const int t    = threadIdx.x;
    const int lane = t & 63;
    const int w    = t >> 6;
    const int ln15 = lane & 15;
    const int q4   = lane >> 4;
    const int bh   = blockIdx.x;

    if (t < 32) ((float4*)qS)[t] = ((const float4*)(query + (size_t)bh * Dd))[t];
    __syncthreads();

    {   // wave w owns d in [32w, 32w+32) for all e (coalesced 256B W_basic loads)
        const int e0 = lane, d0 = w * 32;
#pragma unroll
        for (int c = 0; c < 4; ++c) {
            short pk[8];
#pragma unroll
            for (int j = 0; j < 8; ++j) {
                const int d = d0 + c * 8 + j;
                pk[j] = f2bf(qS[d] * W_basic[d * MIDe + e0]);
            }
            *(bf16x8*)&wqT[e0][d0 + c * 8] = *(bf16x8*)pk;
        }
    }
    __syncthreads();

    // wave w = ks; frag slot fs = bh*16 + ks*4 + nt; addr = fs*512 + lane*8 shorts
    short* dst = wqF + ((size_t)bh * 16 + w * 4) * 512 + lane * 8;
#pragma unroll
    for (int nt = 0; nt < 4; ++nt) {
        const bf16x8 f = *(const bf16x8*)&wqT[nt * 16 + ln15][w * 32 + q4 * 8];
        *(bf16x8*)(dst + nt * 512) = f;
    }
}

// ---------------- K1: per-(bh, m-tile) MFMA, one wave, no LDS, no barriers ----
__global__ __launch_bounds__(64, 3)
void gemm_tile(const float* __restrict__ key,
               const float* __restrict__ att_mask,
               const float* __restrict__ b_basic,
               const float* __restrict__ W_spatial,
               const float* __restrict__ b_spatial,
               const short* __restrict__ wqF,
               float* __restrict__ sW,
               float* __restrict__ poolW)
{
    const int lane = threadIdx.x;
    const int ln15 = lane & 15;
    const int q4   = lane >> 4;
    const int mt   = blockIdx.x;        // 0..12
    const int bh   = blockIdx.y;        // 0..1023
    const int b    = bh >> 3;

    // ---- A loads: key rows, 8x b128, all in flight ----
    const int mrow = min(mt * 16 + ln15, Mm - 1);
    const float* ap = key + ((size_t)bh * Mm + mrow) * Dd + q4 * 8;
    float4 a0[4], a1[4];
#pragma unroll
    for (int ks = 0; ks < 4; ++ks) {
        a0[ks] = *(const float4*)(ap + ks * 32);
        a1[ks] = *(const float4*)(ap + ks * 32 + 4);
    }
    // ---- B loads: 16x b128, perfectly coalesced (1 KB/instr), all in flight ----
    const short* wp = wqF + (size_t)bh * 8192 + lane * 8;
    bf16x8 bfr[16];
#pragma unroll
    for (int i = 0; i < 16; ++i)
        bfr[i] = *(const bf16x8*)(wp + (size_t)i * 512);

    // small epilogue vectors (L2-hot)
    float bbv[4], wspv[4];
#pragma unroll
    for (int nt = 0; nt < 4; ++nt) {
        bbv[nt]  = b_basic[nt * 16 + ln15];
        wspv[nt] = W_spatial[nt * 16 + ln15];
    }
    const float bsp = b_spatial[0];

    f32x4 acc[4] = {f32x4{0,0,0,0}, f32x4{0,0,0,0},
                    f32x4{0,0,0,0}, f32x4{0,0,0,0}};
#pragma unroll
    for (int ks = 0; ks < 4; ++ks) {
        const bf16x8 af = { f2bf(a0[ks].x), f2bf(a0[ks].y),
                            f2bf(a0[ks].z), f2bf(a0[ks].w),
                            f2bf(a1[ks].x), f2bf(a1[ks].y),
                            f2bf(a1[ks].z), f2bf(a1[ks].w) };
#pragma unroll
        for (int nt = 0; nt < 4; ++nt)
            acc[nt] = __builtin_amdgcn_mfma_f32_16x16x32_bf16(
                          af, bfr[ks * 4 + nt], acc[nt], 0, 0, 0);
    }

    // ---- epilogue: relu+bias, s-logit (in-wave reduce), pool partial ----
    float poolAcc[4] = {0.f, 0.f, 0.f, 0.f};
#pragma unroll
    for (int r = 0; r < 4; ++r) {
        const int m = mt * 16 + q4 * 4 + r;
        const bool valid = m < Mm;
        const float msk = valid ? att_mask[b * Mm + m] : 0.f;
        float srow = 0.f;
#pragma unroll
        for (int nt = 0; nt < 4; ++nt) {
            float hv = acc[nt][r] + bbv[nt];
            hv = hv > 0.f ? hv : 0.f;
            poolAcc[nt] = fmaf(hv, msk, poolAcc[nt]);
            srow = fmaf(hv, wspv[nt], srow);
        }
        srow += __shfl_xor(srow, 1, 64);
        srow += __shfl_xor(srow, 2, 64);
        srow += __shfl_xor(srow, 4, 64);
        srow += __shfl_xor(srow, 8, 64);
        if (valid && ln15 == 0) sW[(size_t)bh * SLD + m] = srow + bsp;
    }
#pragma unroll
    for (int nt = 0; nt < 4; ++nt) {
        poolAcc[nt] += __shfl_xor(poolAcc[nt], 16, 64);
        poolAcc[nt] += __shfl_xor(poolAcc[nt], 32, 64);
    }
    if (lane < 16) {
#pragma unroll
        for (int nt = 0; nt < 4; ++nt)
            poolW[(size_t)bh * (NMT * 64) + mt * 64 + nt * 16 + lane] = poolAcc[nt];
    }
}

// ---------------- K2: softmax + pool + gate + value2 contraction + out ----
__global__ __launch_bounds__(256)
void finish(const float* __restrict__ att_mask,
            const float* __restrict__ value1,
            const float* __restrict__ value2,
            const float* __restrict__ W_channel,
            const float* __restrict__ b_channel,
            const float* __restrict__ sW,
            const float* __restrict__ poolW,
            float* __restrict__ out)
{
    __shared__ float sS[Mm];
    __shared__ float poolS[MIDe];
    __shared__ float partS[8][DVv];
    __shared__ float redS[12];

    const int t    = threadIdx.x;
    const int lane = t & 63;
    const int w    = t >> 6;
    const int bh   = blockIdx.x;
    const int b    = bh >> 3;

    const float* __restrict__ val2B = value2 + (size_t)bh * Mm * DVv;

    // ---- masked softmax over m (inputs straight from global; no pre-barrier) ----
    const float myMask = (t < Mm) ? att_mask[b * Mm + t] : 0.f;
    float myS = -3.0e38f;
    if (t < Mm) {
        myS = sW[(size_t)bh * SLD + t];
        if (myMask == 0.f) myS = -1.0e9f;
    }
    const float rmx = waveReduceMax(myS);
    if (lane == 0) redS[w] = rmx;
    __syncthreads();
    const float mx = fmaxf(fmaxf(redS[0], redS[1]), fmaxf(redS[2], redS[3]));
    const float ev = (t < Mm) ? __expf(myS - mx) : 0.f;
    const float s1 = waveReduceSum(ev);
    const float s2 = waveReduceSum(myMask);
    if (lane == 0) { redS[4 + w] = s1; redS[8 + w] = s2; }
    __syncthreads();
    const float denom = redS[4] + redS[5] + redS[6] + redS[7];
    const float cnt   = redS[8] + redS[9] + redS[10] + redS[11];
    if (t < Mm) sS[t] = ev / denom;
    if (t < MIDe) {
        float p = 0.f;
#pragma unroll
        for (int mt = 0; mt < NMT; ++mt)
            p += poolW[(size_t)bh * (NMT * 64) + mt * 64 + t];
        poolS[t] = p / cnt;
    }
    __syncthreads();

    // ---- channel gate (threads 0..127), kept in register ----
    float chv = 0.f;
    if (t < DVv) {
        float a = b_channel[t];
#pragma unroll 16
        for (int e = 0; e < MIDe; ++e)
            a = fmaf(poolS[e], W_channel[e * DVv + t], a);
        chv = 1.f / (1.f + __expf(-a));
    }

    // ---- v2 = alpha @ value2: fixed-trip guarded loop -> deep load batch ----
    const int vq = t & 31;   // float4 column
    const int ms = t >> 5;   // m-stripe 0..7
    float4 acc4 = make_float4(0.f, 0.f, 0.f, 0.f);
#pragma unroll
    for (int i = 0; i < 25; ++i) {
        const int m = ms + 8 * i;
        if (m < Mm) {
            const float a = sS[m];
            const float4 vv = *(const float4*)(val2B + (size_t)m * DVv + 4 * vq);
            acc4.x = fmaf(a, vv.x, acc4.x);
            acc4.y = fmaf(a, vv.y, acc4.y);
            acc4.z = fmaf(a, vv.z, acc4.z);
            acc4.w = fmaf(a, vv.w, acc4.w);
        }
    }
    ((float4*)&partS[ms][0])[vq] = acc4;
    __syncthreads();

    if (t < DVv) {
        float v2v = 0.f;
#pragma unroll
        for (int i = 0; i < 8; ++i) v2v += partS[i][t];
        out[(size_t)bh * DVv + t] = value1[(size_t)bh * DVv + t] * v2v * chv;
    }
}

extern "C" void kernel_launch(void* const* d_in, const int* in_sizes, int n_in,
                              void* d_out, int out_size, void* d_ws, size_t ws_size,
                              hipStream_t stream) {
    const float* query     = (const float*)d_in[0];
    const float* key       = (const float*)d_in[1];
    const float* att_mask  = (const float*)d_in[2];
    const float* value1    = (const float*)d_in[3];
    const float* value2    = (const float*)d_in[4];
    const float* W_basic   = (const float*)d_in[5];
    const float* b_basic   = (const float*)d_in[6];
    const float* W_spatial = (const float*)d_in[7];
    const float* b_spatial = (const float*)d_in[8];
    const float* W_channel = (const float*)d_in[9];
    const float* b_channel = (const float*)d_in[10];
    float* out = (float*)d_out;

    short* wqF  = (short*)d_ws;
    float* sW   = (float*)((char*)d_ws + WQ_SHORTS * sizeof(short));
    float* poolW = sW + SW_FLOATS;

    build_wq<<<NBH, 256, 0, stream>>>(query, W_basic, wqF);
    gemm_tile<<<dim3(NMT, NBH), 64, 0, stream>>>(key, att_mask, b_basic,
                                                 W_spatial, b_spatial,
                                                 wqF, sW, poolW);
    finish<<<NBH, 256, 0, stream>>>(att_mask, value1, value2, W_channel,
                                    b_channel, sW, poolW, out);
}

// Round 6
// 246.722 us; speedup vs baseline: 1.0537x; 1.0537x over previous
//
#include <hip/hip_runtime.h>
#include <cstddef>

// Problem shapes (fixed by reference)
#define NBH  1024   // B*H
#define Mm   196
#define Dd   128
#define MIDe 64
#define DVv  128

typedef __attribute__((ext_vector_type(8))) short bf16x8;  // 8 bf16 in 4 VGPRs
typedef __attribute__((ext_vector_type(4))) float f32x4;   // MFMA C/D frag

__device__ __forceinline__ short f2bf(float x) {           // fp32 -> bf16 RNE
    union { float f; unsigned u; } v; v.f = x;
    return (short)((v.u + 0x7FFFu + ((v.u >> 16) & 1u)) >> 16);
}

__device__ __forceinline__ float waveReduceSum(float v) {
#pragma unroll
    for (int off = 32; off > 0; off >>= 1) v += __shfl_xor(v, off, 64);
    return v;
}

__device__ __forceinline__ float waveReduceMax(float v) {
#pragma unroll
    for (int off = 32; off > 0; off >>= 1) v = fmaxf(v, __shfl_xor(v, off, 64));
    return v;
}

__global__ __launch_bounds__(256, 3)
void scatt_fused(const float* __restrict__ query,
                 const float* __restrict__ key,
                 const float* __restrict__ att_mask,
                 const float* __restrict__ value1,
                 const float* __restrict__ value2,
                 const float* __restrict__ W_basic,
                 const float* __restrict__ b_basic,
                 const float* __restrict__ W_spatial,
                 const float* __restrict__ b_spatial,
                 const float* __restrict__ W_channel,
                 const float* __restrict__ b_channel,
                 float* __restrict__ out)
{
    __shared__ short wqT[MIDe][136];    // bf16 Wq^T[e][d], +8-short row pad
    __shared__ float qS[Dd];
    __shared__ float maskS[Mm];
    __shared__ float sS[Mm];            // spatial logits, then alpha (in place)
    __shared__ float poolPart[4][MIDe];
    __shared__ float poolS[MIDe];
    __shared__ float partS[8][DVv];     // v2 partial sums
    __shared__ float redS[12];

    const int t    = threadIdx.x;
    const int lane = t & 63;
    const int w    = t >> 6;            // wave id 0..3
    const int ln15 = lane & 15;
    const int q4   = lane >> 4;         // quad id 0..3
    const int bh   = blockIdx.x;
    const int b    = bh >> 3;

    const float* __restrict__ keyB  = key      + (size_t)bh * Mm * Dd;
    const float* __restrict__ val2B = value2   + (size_t)bh * Mm * DVv;
    const float* __restrict__ qB    = query    + (size_t)bh * Dd;
    const float* __restrict__ maskB = att_mask + (size_t)b  * Mm;

    // ---- Phase 0a: stage q + mask ----
    if (t < 32) ((float4*)qS)[t] = ((const float4*)qB)[t];
    for (int i = t; i < Mm; i += 256) maskS[i] = maskB[i];
    __syncthreads();

    // ---- Phase 0b: build WqT[e][d] = bf16(q[d]*W_basic[d][e]) cooperatively.
    // Wave w owns d in [32w, 32w+32): coalesced 256B W_basic row loads (lane=e).
    {
        const int e0 = lane, d0 = w * 32;
#pragma unroll
        for (int c = 0; c < 4; ++c) {
            short pk[8];
#pragma unroll
            for (int j = 0; j < 8; ++j) {
                const int d = d0 + c * 8 + j;
                pk[j] = f2bf(qS[d] * W_basic[d * MIDe + e0]);
            }
            *(bf16x8*)&wqT[e0][d0 + c * 8] = *(bf16x8*)pk;  // ds_write_b128
        }
    }

    // epilogue vectors (tiny, L2-hot)
    float bbv[4], wspv[4];
#pragma unroll
    for (int nt = 0; nt < 4; ++nt) {
        bbv[nt]  = b_basic[nt * 16 + ln15];
        wspv[nt] = W_spatial[nt * 16 + ln15];
    }
    const float bsp = b_spatial[0];
    float poolAcc[4] = {0.f, 0.f, 0.f, 0.f};

    // ---- Phase 1: h = relu(key @ Wq + b) via MFMA, software-pipelined.
    // Wave w owns m-tiles {w, w+4, w+8, w+12<13}. A-loads of tile t+1 are
    // issued into named registers BEFORE tile t's compute, so 8x b128 stay
    // in flight per wave throughout. B-frags re-read from LDS per tile
    // (16x ds_read_b128, cheap) instead of pinning 64 VGPRs.
    auto loadA = [&](int mt_, float4* x0, float4* x1) {
        const int mrow = min(mt_ * 16 + ln15, Mm - 1);
        const float* ap = keyB + (size_t)mrow * Dd + q4 * 8;
#pragma unroll
        for (int ks = 0; ks < 4; ++ks) {
            x0[ks] = *(const float4*)(ap + ks * 32);
            x1[ks] = *(const float4*)(ap + ks * 32 + 4);
        }
    };

    float4 a0[4], a1[4];
    loadA(w, a0, a1);            // prefetch first tile (before the barrier:
    __syncthreads();             // loads don't touch LDS; barrier covers wqT)

    for (int mt = w; mt < 13; mt += 4) {
        // prefetch next tile while this tile computes
        float4 n0[4], n1[4];
        const int mtn = mt + 4;
        if (mtn < 13) loadA(mtn, n0, n1);

        f32x4 acc[4] = {f32x4{0,0,0,0}, f32x4{0,0,0,0},
                        f32x4{0,0,0,0}, f32x4{0,0,0,0}};
#pragma unroll
        for (int ks = 0; ks < 4; ++ks) {
            const bf16x8 af = { f2bf(a0[ks].x), f2bf(a0[ks].y),
                                f2bf(a0[ks].z), f2bf(a0[ks].w),
                                f2bf(a1[ks].x), f2bf(a1[ks].y),
                                f2bf(a1[ks].z), f2bf(a1[ks].w) };
#pragma unroll
            for (int nt = 0; nt < 4; ++nt) {
                const bf16x8 bf =
                    *(const bf16x8*)&wqT[nt * 16 + ln15][ks * 32 + q4 * 8];
                acc[nt] = __builtin_amdgcn_mfma_f32_16x16x32_bf16(
                              af, bf, acc[nt], 0, 0, 0);
            }
        }

        // Epilogue: C/D layout col = ln15 (e within n-tile), row = q4*4 + r.
#pragma unroll
        for (int r = 0; r < 4; ++r) {
            const int m = mt * 16 + q4 * 4 + r;
            const bool valid = m < Mm;
            const float msk = valid ? maskS[m] : 0.f;
            float srow = 0.f;
#pragma unroll
            for (int nt = 0; nt < 4; ++nt) {
                float hv = acc[nt][r] + bbv[nt];
                hv = hv > 0.f ? hv : 0.f;                 // relu
                poolAcc[nt] = fmaf(hv, msk, poolAcc[nt]); // masked pool partial
                srow = fmaf(hv, wspv[nt], srow);          // h[m,:].W_spatial
            }
            srow += __shfl_xor(srow, 1, 64);
            srow += __shfl_xor(srow, 2, 64);
            srow += __shfl_xor(srow, 4, 64);
            srow += __shfl_xor(srow, 8, 64);
            if (valid && ln15 == 0) sS[m] = srow + bsp;
        }
#pragma unroll
        for (int ks = 0; ks < 4; ++ks) { a0[ks] = n0[ks]; a1[ks] = n1[ks]; }
    }
    // pool: reduce the 4 row-quads (same e, different m) across q4
#pragma unroll
    for (int nt = 0; nt < 4; ++nt) {
        poolAcc[nt] += __shfl_xor(poolAcc[nt], 16, 64);
        poolAcc[nt] += __shfl_xor(poolAcc[nt], 32, 64);
    }
    if (lane < 16) {
#pragma unroll
        for (int nt = 0; nt < 4; ++nt)
            poolPart[w][nt * 16 + lane] = poolAcc[nt];
    }
    __syncthreads();

    // ---- Phase 2: masked softmax over m; finalize pool ----
    const float myMask = (t < Mm) ? maskS[t] : 0.f;
    float myS = -3.0e38f;
    if (t < Mm) {
        myS = sS[t];
        if (myMask == 0.f) myS = -1.0e9f;
    }
    const float rmx = waveReduceMax(myS);
    if (lane == 0) redS[w] = rmx;
    __syncthreads();
    const float mx = fmaxf(fmaxf(redS[0], redS[1]), fmaxf(redS[2], redS[3]));
    const float ev = (t < Mm) ? __expf(myS - mx) : 0.f;
    const float s1 = waveReduceSum(ev);
    const float s2 = waveReduceSum(myMask);
    if (lane == 0) { redS[4 + w] = s1; redS[8 + w] = s2; }
    __syncthreads();
    const float denom = redS[4] + redS[5] + redS[6] + redS[7];
    const float cnt   = redS[8] + redS[9] + redS[10] + redS[11];
    if (t < Mm) sS[t] = ev / denom;   // alpha, in place (all reads done pre-sync)
    if (t < MIDe)
        poolS[t] = (poolPart[0][t] + poolPart[1][t] + poolPart[2][t] + poolPart[3][t]) / cnt;
    __syncthreads();

    // ---- Phase 3a: channel gate (threads 0..127), kept in register ----
    float chv = 0.f;
    if (t < DVv) {
        float a = b_channel[t];
#pragma unroll 16
        for (int e = 0; e < MIDe; ++e)
            a = fmaf(poolS[e], W_channel[e * DVv + t], a);  // coalesced over t
        chv = 1.f / (1.f + __expf(-a));
    }

    // ---- Phase 3b: v2 = alpha @ value2; fixed-trip guarded -> deep batches ----
    const int vq = t & 31;   // float4 column
    const int ms = t >> 5;   // m-stripe 0..7
    float4 acc4 = make_float4(0.f, 0.f, 0.f, 0.f);
#pragma unroll
    for (int i = 0; i < 25; ++i) {
        const int m = ms + 8 * i;
        if (m < Mm) {
            const float a = sS[m];
            const float4 vv = *(const float4*)(val2B + (size_t)m * DVv + 4 * vq);
            acc4.x = fmaf(a, vv.x, acc4.x);
            acc4.y = fmaf(a, vv.y, acc4.y);
            acc4.z = fmaf(a, vv.z, acc4.z);
            acc4.w = fmaf(a, vv.w, acc4.w);
        }
    }
    ((float4*)&partS[ms][0])[vq] = acc4;
    __syncthreads();

    // ---- Epilogue: out = value1 * v2 * channel_gate ----
    if (t < DVv) {
        float v2v = 0.f;
#pragma unroll
        for (int i = 0; i < 8; ++i) v2v += partS[i][t];
        out[(size_t)bh * DVv + t] = value1[(size_t)bh * DVv + t] * v2v * chv;
    }
}

extern "C" void kernel_launch(void* const* d_in, const int* in_sizes, int n_in,
                              void* d_out, int out_size, void* d_ws, size_t ws_size,
                              hipStream_t stream) {
    const float* query     = (const float*)d_in[0];
    const float* key       = (const float*)d_in[1];
    const float* att_mask  = (const float*)d_in[2];
    const float* value1    = (const float*)d_in[3];
    const float* value2    = (const float*)d_in[4];
    const float* W_basic   = (const float*)d_in[5];
    const float* b_basic   = (const float*)d_in[6];
    const float* W_spatial = (const float*)d_in[7];
    const float* b_spatial = (const float*)d_in[8];
    const float* W_channel = (const float*)d_in[9];
    const float* b_channel = (const float*)d_in[10];
    float* out = (float*)d_out;

    scatt_fused<<<NBH, 256, 0, stream>>>(query, key, att_mask, value1, value2,
                                         W_basic, b_basic, W_spatial, b_spatial,
                                         W_channel, b_channel, out);
}